// Round 9
// baseline (1385.470 us; speedup 1.0000x reference)
//
#include <hip/hip_runtime.h>

// Problem constants
#define N_VERT 5000
#define NCOL   12288      // B*T*C_OUT reinterpreted columns
#define KPAD   5056       // 79*64: K padded (zero-filled)
#define MPAD   5120       // 20*256: M padded

#define G1_BLOCKS  15168  // 79*192 gemm1 blocks
#define CVT_BLOCKS 25280  // MPAD*(KPAD/4)/256

typedef float          f32x4  __attribute__((ext_vector_type(4)));
typedef unsigned short u16x4  __attribute__((ext_vector_type(4)));
typedef __bf16         bf16x8 __attribute__((ext_vector_type(8)));

__device__ __forceinline__ unsigned short f2bf(float f) {
  unsigned int u = __builtin_bit_cast(unsigned int, f);
  u += 0x7fffu + ((u >> 16) & 1u);   // RNE
  return (unsigned short)(u >> 16);
}

__device__ __forceinline__ void async16(const unsigned short* g, unsigned short* l) {
  __builtin_amdgcn_global_load_lds(
      (const __attribute__((address_space(1))) unsigned int*)g,
      (__attribute__((address_space(3))) unsigned int*)l, 16, 0, 0);
}

// ---------------------------------------------------------------------------
// Kernel P (merged prep, R7 MFMA version — measured at streaming floor):
// blocks [0, G1_BLOCKS) run GEMM1 (x@W -> Ht = H^T [col][KPAD], bf16) via
// MFMA with x split hi/lo bf16 (precision ~= fp32 GEMM); blocks
// [G1_BLOCKS, +CVT_BLOCKS) convert F -> Fb bf16 [MPAD][KPAD].
// ---------------------------------------------------------------------------
__global__ __launch_bounds__(256) void prep(const float* __restrict__ x,
                                            const float* __restrict__ W,
                                            const float* __restrict__ F,
                                            unsigned short* __restrict__ Ht,
                                            unsigned short* __restrict__ Fb) {
  __shared__ unsigned short xh[64][72];   // x hi bf16, [u][c]
  __shared__ unsigned short xl[64][72];   // x lo bf16
  __shared__ unsigned short Wt[64][72];   // W^T bf16, [j][c]
  const int tid = threadIdx.x;

  if (blockIdx.x >= G1_BLOCKS) {
    int idx = (blockIdx.x - G1_BLOCKS) * 256 + tid;
    int row = idx / (KPAD / 4);
    int c4  = (idx % (KPAD / 4)) * 4;
    u16x4 o;
    if (row < N_VERT && c4 < N_VERT) {
      f32x4 v = *(const f32x4*)(F + (long)row * N_VERT + c4);
      o.x = f2bf(v.x); o.y = f2bf(v.y); o.z = f2bf(v.z); o.w = f2bf(v.w);
    } else {
      o.x = 0; o.y = 0; o.z = 0; o.w = 0;
    }
    *(u16x4*)(Fb + (long)row * KPAD + c4) = o;
    return;
  }

  const int utile = blockIdx.x % 79;   // 0..78
  const int rr    = blockIdx.x / 79;   // 0..191

  // W[c][j] -> Wt[j][c] bf16 (coalesced global read; scalar LDS store)
  for (int i = tid; i < 4096; i += 256) Wt[i & 63][i >> 6] = f2bf(W[i]);

  // x rows (u fixed, 64 c contiguous) -> xh/xl straight [u][c]
  {
    int rowu = tid >> 2;
    int cb   = (tid & 3) * 16;
    long u   = (long)utile * 64 + rowu;
    bool valid = (u < N_VERT);
    const float* src = x + (u * 192 + rr) * 64;
#pragma unroll
    for (int q = 0; q < 4; ++q) {
      int col = cb + q * 4;
      f32x4 v = {0.f, 0.f, 0.f, 0.f};
      if (valid) v = *(const f32x4*)(src + col);
      u16x4 h, lo;
#pragma unroll
      for (int e = 0; e < 4; ++e) {
        unsigned short hb = f2bf(v[e]);
        float hf = __builtin_bit_cast(float, (unsigned int)hb << 16);
        h[e]  = hb;
        lo[e] = f2bf(v[e] - hf);
      }
      *(u16x4*)&xh[rowu][col] = h;
      *(u16x4*)&xl[rowu][col] = lo;
    }
  }
  __syncthreads();

  // 4 waves; wave w owns j-block w*16. D[u][j] = x[u][c] @ W[c][j].
  const int l  = tid & 63;
  const int w  = tid >> 6;
  const int la = l & 15;
  const int ch = l >> 4;
  const int jb = w * 16;

  const char* xhp = (const char*)xh;
  const char* xlp = (const char*)xl;
  const char* wtp = (const char*)Wt;

  f32x4 acc[4] = {};
#pragma unroll
  for (int ks = 0; ks < 2; ++ks) {
    const int ko = ks * 64 + ch * 16;
    bf16x8 bfr = *(const bf16x8*)(wtp + (jb + la) * 144 + ko);
#pragma unroll
    for (int a = 0; a < 4; ++a) {
      bf16x8 al = *(const bf16x8*)(xlp + (a * 16 + la) * 144 + ko);
      bf16x8 ah = *(const bf16x8*)(xhp + (a * 16 + la) * 144 + ko);
      acc[a] = __builtin_amdgcn_mfma_f32_16x16x32_bf16(al, bfr, acc[a], 0, 0, 0);
      acc[a] = __builtin_amdgcn_mfma_f32_16x16x32_bf16(ah, bfr, acc[a], 0, 0, 0);
    }
  }

  // Store: lane l covers col = rr*64 + jb + la, k = utile*64 + a*16 + ch*4 + reg
  const long col = (long)rr * 64 + jb + la;
  const long kb  = (long)utile * 64 + ch * 4;
#pragma unroll
  for (int a = 0; a < 4; ++a) {
    u16x4 o = {f2bf(acc[a][0]), f2bf(acc[a][1]), f2bf(acc[a][2]), f2bf(acc[a][3])};
    *(u16x4*)(Ht + col * KPAD + kb + a * 16) = o;
  }
}

// ---------------------------------------------------------------------------
// Kernel 3: GEMM2  agg = F @ H (+bias). 256x256 tile, BK=64. *** R9: 4 waves
// (2Mx2N), wave tile 128x128, acc 8x8 f32x4 (256 VGPR), 1 wave/SIMD
// (__launch_bounds__(256,1)). Per-tile LDS read volume drops 192KB -> 128KB
// (A amp 4->2) with MFMA work unchanged; the sum-of-pipes wall (306us MFMA +
// 284us LDS ~= 551us measured at 8 waves) predicts ~465us at 128KB. ***
// Everything else is the R0-verified kernel transformed mechanically:
// same 3-phase schedule, same swizzle constants, same XCD map.
//  PH0: read afL(8) + b1(8); 64 MFMA m0-3 x n0-7; bar
//  PH1: read afH(8); stage B(t+2) 8 DMA; 32 MFMA m4-7 x b0; bar
//  PH2: stage A(t+2) 8 DMA; vmcnt(16); bar; b0(t+1) cross-read(8);
//       32 MFMA m4-7 x b1
// Hazards (R0 invariants, 16 DMA/tile): B(bi) last read b1@PH0 -> staged PH1
// after PH0's barrier; A(bi) last read afH@PH1 -> staged PH2 after PH1's
// barrier. vmcnt(16)+bar: outstanding <=16 = t+2's own 16 -> t+1 fully
// landed before the b0(t+1) cross-read.
// Per wave/tile: 32 ds_read_b128, 16 DMA, 128 MFMA.
// ---------------------------------------------------------------------------
__global__ __launch_bounds__(256, 1) void gemm2(const unsigned short* __restrict__ A,
                                                const unsigned short* __restrict__ Bt,
                                                const float* __restrict__ bias,
                                                float* __restrict__ out) {
  __shared__ __align__(16) char sm[131072];   // 2 x (A 32KB + B 32KB)

  const int tid = threadIdx.x;
  const int l   = tid & 63;
  const int w   = tid >> 6;        // wave 0..3
  const int wr  = w >> 1;          // 0..1  (M)
  const int wc  = w & 1;           // 0..1  (N)
  const int la  = l & 15;

  // Locality-grouped XCD swizzle (R0-verified: FETCH ~546MB)
  const int xcd = blockIdx.x & 7;
  const int ii  = blockIdx.x >> 3;
  const int gg  = ii / 30;
  const int rmap= ii % 30;
  const long tM = (long)(gg * 5 + (rmap % 5)) * 256;
  const long tN = (long)(xcd * 6 + (rmap / 5)) * 256;

  // --- staging source (pre-swizzled global address; LDS dest linear; R0) ---
  const int  sRow  = l >> 3;
  const int  sCol8 = ((l & 7) ^ (l >> 3)) * 8;
  const unsigned short* gA2 = A  + (tM + sRow) * (size_t)KPAD + sCol8;
  const unsigned short* gB2 = Bt + (tN + sRow) * (size_t)KPAD + sCol8;

  // 8 loads covering 256 rows of one operand region (wave w: rows w*64..+63)
  auto stage8 = [&](int bufB, const unsigned short* g, int regionOff) {
#pragma unroll
    for (int q = 0; q < 8; ++q)
      async16(g + (size_t)(w * 64 + q * 8) * KPAD,
              (unsigned short*)(sm + bufB + regionOff + w * 8192 + q * 1024));
  };

  // --- hoisted swizzled ds_read base pointers (reads = base + frag*2048) ---
  const int cOff0 = ((l >> 4) * 16)      ^ ((l & 7) << 4);
  const int cOff1 = (64 + (l >> 4) * 16) ^ ((l & 7) << 4);
  const int aRow  = (wr * 128 + la) * 128;
  const int bRow  = 32768 + (wc * 128 + la) * 128;
  const char* pA0[2] = { sm + aRow + cOff0, sm + 65536 + aRow + cOff0 };
  const char* pA1[2] = { sm + aRow + cOff1, sm + 65536 + aRow + cOff1 };
  const char* pB0[2] = { sm + bRow + cOff0, sm + 65536 + bRow + cOff0 };
  const char* pB1[2] = { sm + bRow + cOff1, sm + 65536 + bRow + cOff1 };

  f32x4  acc[8][8] = {};
  bf16x8 af[4][2], b0[4][2], b1[4][2];

  // mode: 0 steady; 1 = t=77 (no stage, vmcnt(0)); 2 = t=78 (tail).
  auto tile = [&](int bi, int mode) {
    const int bo = bi << 16;
    const int ni = bi ^ 1;
    // ==== PH0: read afL(8) + b1(8); 64 MFMA m0-3 x (b0,b1) ====
#pragma unroll
    for (int i2 = 0; i2 < 4; ++i2) {
      af[i2][0] = *(const bf16x8*)(pA0[bi] + i2 * 2048);
      af[i2][1] = *(const bf16x8*)(pA1[bi] + i2 * 2048);
    }
#pragma unroll
    for (int j = 0; j < 4; ++j) {
      b1[j][0] = *(const bf16x8*)(pB0[bi] + (4 + j) * 2048);
      b1[j][1] = *(const bf16x8*)(pB1[bi] + (4 + j) * 2048);
    }
    __builtin_amdgcn_s_setprio(1);
#pragma unroll
    for (int ks = 0; ks < 2; ++ks)
#pragma unroll
      for (int i2 = 0; i2 < 4; ++i2) {
#pragma unroll
        for (int j2 = 0; j2 < 4; ++j2)
          acc[i2][j2] = __builtin_amdgcn_mfma_f32_16x16x32_bf16(
              af[i2][ks], b0[j2][ks], acc[i2][j2], 0, 0, 0);
#pragma unroll
        for (int j2 = 0; j2 < 4; ++j2)
          acc[i2][4 + j2] = __builtin_amdgcn_mfma_f32_16x16x32_bf16(
              af[i2][ks], b1[j2][ks], acc[i2][4 + j2], 0, 0, 0);
      }
    __builtin_amdgcn_s_setprio(0);
    __builtin_amdgcn_s_barrier();
    // ==== PH1: read afH(8); stage B(t+2) -> bo; 32 MFMA m4-7 x b0 ====
#pragma unroll
    for (int i2 = 0; i2 < 4; ++i2) {
      af[i2][0] = *(const bf16x8*)(pA0[bi] + (4 + i2) * 2048);
      af[i2][1] = *(const bf16x8*)(pA1[bi] + (4 + i2) * 2048);
    }
    if (mode == 0) {
      stage8(bo, gB2, 32768);
      gB2 += 64;
    }
    __builtin_amdgcn_s_setprio(1);
#pragma unroll
    for (int ks = 0; ks < 2; ++ks)
#pragma unroll
      for (int i2 = 0; i2 < 4; ++i2)
#pragma unroll
        for (int j2 = 0; j2 < 4; ++j2)
          acc[4 + i2][j2] = __builtin_amdgcn_mfma_f32_16x16x32_bf16(
              af[i2][ks], b0[j2][ks], acc[4 + i2][j2], 0, 0, 0);
    __builtin_amdgcn_s_setprio(0);
    __builtin_amdgcn_s_barrier();
    // ==== PH2: stage A(t+2) -> bo; vmcnt(16); bar; b0(t+1); 32 MFMA m4-7 x b1 ====
    if (mode == 0) {
      stage8(bo, gA2, 0);
      gA2 += 64;
      asm volatile("s_waitcnt vmcnt(16)" ::: "memory");   // t+1 fully landed
    } else if (mode == 1) {
      asm volatile("s_waitcnt vmcnt(0)" ::: "memory");
    }
    __builtin_amdgcn_s_barrier();                         // globalizes vmcnt
    __builtin_amdgcn_sched_barrier(0);                    // pin reads below
    if (mode != 2) {
#pragma unroll
      for (int j = 0; j < 4; ++j) {
        b0[j][0] = *(const bf16x8*)(pB0[ni] + j * 2048);  // b0(t+1)
        b0[j][1] = *(const bf16x8*)(pB1[ni] + j * 2048);
      }
    }
    __builtin_amdgcn_s_setprio(1);
#pragma unroll
    for (int ks = 0; ks < 2; ++ks)
#pragma unroll
      for (int i2 = 0; i2 < 4; ++i2)
#pragma unroll
        for (int j2 = 0; j2 < 4; ++j2)
          acc[4 + i2][4 + j2] = __builtin_amdgcn_mfma_f32_16x16x32_bf16(
              af[i2][ks], b1[j2][ks], acc[4 + i2][4 + j2], 0, 0, 0);
    __builtin_amdgcn_s_setprio(0);
    // no trailing barrier: next PH0's reads are covered by this vmcnt+bar
  };

  // ---- prologue: stage t0 -> buf0, t1 -> buf1; pre-read b0(0) ----
  stage8(0, gB2, 32768);     stage8(0, gA2, 0);
  gA2 += 64; gB2 += 64;
  stage8(65536, gB2, 32768); stage8(65536, gA2, 0);
  gA2 += 64; gB2 += 64;       // -> tile 2 (first in-loop stage target)
  asm volatile("s_waitcnt vmcnt(16)" ::: "memory");   // t0's 16 loads retired
  __builtin_amdgcn_s_barrier();
  __builtin_amdgcn_sched_barrier(0);
#pragma unroll
  for (int j = 0; j < 4; ++j) {
    b0[j][0] = *(const bf16x8*)(pB0[0] + j * 2048);
    b0[j][1] = *(const bf16x8*)(pB1[0] + j * 2048);
  }

  // ---- main loop: t = 0..78 (79 K-tiles) ----
#pragma unroll 1
  for (int it = 0; it < 38; ++it) {    // t = 0..75
    tile(0, 0);
    tile(1, 0);
  }
  tile(0, 0);   // t=76: stages tile 78 into buf0
  tile(1, 1);   // t=77: drain, read b0(78) from buf0
  tile(0, 2);   // t=78: last

  // ---- epilogue: C/D map col=lane&15, row=(lane>>4)*4+reg ----
  float bv[4];
#pragma unroll
  for (int n = 0; n < 4; ++n) bv[n] = bias[n * 16 + la];
  const int rb = (l >> 4) * 4;
#pragma unroll
  for (int m = 0; m < 8; ++m) {
    long gm0 = tM + wr * 128 + m * 16 + rb;
#pragma unroll
    for (int rr2 = 0; rr2 < 4; ++rr2) {
      long gm = gm0 + rr2;
      if (gm < N_VERT) {
#pragma unroll
        for (int n = 0; n < 8; ++n) {
          long gn = tN + wc * 128 + n * 16 + la;
          out[gm * NCOL + gn] = acc[m][n][rr2] + bv[n & 3];
        }
      }
    }
  }
}

extern "C" void kernel_launch(void* const* d_in, const int* in_sizes, int n_in,
                              void* d_out, int out_size, void* d_ws, size_t ws_size,
                              hipStream_t stream) {
  const float* x    = (const float*)d_in[0];
  const float* F    = (const float*)d_in[1];
  const float* W    = (const float*)d_in[2];
  const float* bias = (const float*)d_in[3];
  float* out = (float*)d_out;

  const size_t fbB = (size_t)MPAD * KPAD * 2;
  const size_t htB = (size_t)NCOL * KPAD * 2;
  if (ws_size < fbB + htB) return;

  unsigned short* Fb = (unsigned short*)d_ws;
  unsigned short* Ht = (unsigned short*)((char*)d_ws + fbB);

  prep <<<dim3(G1_BLOCKS + CVT_BLOCKS), 256, 0, stream>>>(x, W, F, Ht, Fb);
  gemm2<<<dim3(960),                    256, 0, stream>>>(Fb, Ht, bias, out);
}

// Round 10
// 1292.022 us; speedup vs baseline: 1.0723x; 1.0723x over previous
//
#include <hip/hip_runtime.h>

// Problem constants
#define N_VERT 5000
#define NCOL   12288      // B*T*C_OUT reinterpreted columns
#define KPAD   5056       // 79*64: K padded (zero-filled)
#define MPAD   5120       // 16*320: M padded

#define G1_BLOCKS  15168  // 79*192 gemm1 blocks
#define CVT_BLOCKS 25280  // MPAD*(KPAD/4)/256

typedef float          f32x4  __attribute__((ext_vector_type(4)));
typedef unsigned short u16x4  __attribute__((ext_vector_type(4)));
typedef __bf16         bf16x8 __attribute__((ext_vector_type(8)));

__device__ __forceinline__ unsigned short f2bf(float f) {
  unsigned int u = __builtin_bit_cast(unsigned int, f);
  u += 0x7fffu + ((u >> 16) & 1u);   // RNE
  return (unsigned short)(u >> 16);
}

__device__ __forceinline__ void async16(const unsigned short* g, unsigned short* l) {
  __builtin_amdgcn_global_load_lds(
      (const __attribute__((address_space(1))) unsigned int*)g,
      (__attribute__((address_space(3))) unsigned int*)l, 16, 0, 0);
}

// ---------------------------------------------------------------------------
// Kernel P (merged prep, R7 MFMA version — measured at streaming floor):
// blocks [0, G1_BLOCKS) run GEMM1 (x@W -> Ht = H^T [col][KPAD], bf16) via
// MFMA with x split hi/lo bf16 (precision ~= fp32 GEMM); blocks
// [G1_BLOCKS, +CVT_BLOCKS) convert F -> Fb bf16 [MPAD][KPAD].
// ---------------------------------------------------------------------------
__global__ __launch_bounds__(256) void prep(const float* __restrict__ x,
                                            const float* __restrict__ W,
                                            const float* __restrict__ F,
                                            unsigned short* __restrict__ Ht,
                                            unsigned short* __restrict__ Fb) {
  __shared__ unsigned short xh[64][72];   // x hi bf16, [u][c]
  __shared__ unsigned short xl[64][72];   // x lo bf16
  __shared__ unsigned short Wt[64][72];   // W^T bf16, [j][c]
  const int tid = threadIdx.x;

  if (blockIdx.x >= G1_BLOCKS) {
    int idx = (blockIdx.x - G1_BLOCKS) * 256 + tid;
    int row = idx / (KPAD / 4);
    int c4  = (idx % (KPAD / 4)) * 4;
    u16x4 o;
    if (row < N_VERT && c4 < N_VERT) {
      f32x4 v = *(const f32x4*)(F + (long)row * N_VERT + c4);
      o.x = f2bf(v.x); o.y = f2bf(v.y); o.z = f2bf(v.z); o.w = f2bf(v.w);
    } else {
      o.x = 0; o.y = 0; o.z = 0; o.w = 0;
    }
    *(u16x4*)(Fb + (long)row * KPAD + c4) = o;
    return;
  }

  const int utile = blockIdx.x % 79;   // 0..78
  const int rr    = blockIdx.x / 79;   // 0..191

  // W[c][j] -> Wt[j][c] bf16 (coalesced global read; scalar LDS store)
  for (int i = tid; i < 4096; i += 256) Wt[i & 63][i >> 6] = f2bf(W[i]);

  // x rows (u fixed, 64 c contiguous) -> xh/xl straight [u][c]
  {
    int rowu = tid >> 2;
    int cb   = (tid & 3) * 16;
    long u   = (long)utile * 64 + rowu;
    bool valid = (u < N_VERT);
    const float* src = x + (u * 192 + rr) * 64;
#pragma unroll
    for (int q = 0; q < 4; ++q) {
      int col = cb + q * 4;
      f32x4 v = {0.f, 0.f, 0.f, 0.f};
      if (valid) v = *(const f32x4*)(src + col);
      u16x4 h, lo;
#pragma unroll
      for (int e = 0; e < 4; ++e) {
        unsigned short hb = f2bf(v[e]);
        float hf = __builtin_bit_cast(float, (unsigned int)hb << 16);
        h[e]  = hb;
        lo[e] = f2bf(v[e] - hf);
      }
      *(u16x4*)&xh[rowu][col] = h;
      *(u16x4*)&xl[rowu][col] = lo;
    }
  }
  __syncthreads();

  // 4 waves; wave w owns j-block w*16. D[u][j] = x[u][c] @ W[c][j].
  const int l  = tid & 63;
  const int w  = tid >> 6;
  const int la = l & 15;
  const int ch = l >> 4;
  const int jb = w * 16;

  const char* xhp = (const char*)xh;
  const char* xlp = (const char*)xl;
  const char* wtp = (const char*)Wt;

  f32x4 acc[4] = {};
#pragma unroll
  for (int ks = 0; ks < 2; ++ks) {
    const int ko = ks * 64 + ch * 16;
    bf16x8 bfr = *(const bf16x8*)(wtp + (jb + la) * 144 + ko);
#pragma unroll
    for (int a = 0; a < 4; ++a) {
      bf16x8 al = *(const bf16x8*)(xlp + (a * 16 + la) * 144 + ko);
      bf16x8 ah = *(const bf16x8*)(xhp + (a * 16 + la) * 144 + ko);
      acc[a] = __builtin_amdgcn_mfma_f32_16x16x32_bf16(al, bfr, acc[a], 0, 0, 0);
      acc[a] = __builtin_amdgcn_mfma_f32_16x16x32_bf16(ah, bfr, acc[a], 0, 0, 0);
    }
  }

  // Store: lane l covers col = rr*64 + jb + la, k = utile*64 + a*16 + ch*4 + reg
  const long col = (long)rr * 64 + jb + la;
  const long kb  = (long)utile * 64 + ch * 4;
#pragma unroll
  for (int a = 0; a < 4; ++a) {
    u16x4 o = {f2bf(acc[a][0]), f2bf(acc[a][1]), f2bf(acc[a][2]), f2bf(acc[a][3])};
    *(u16x4*)(Ht + col * KPAD + kb + a * 16) = o;
  }
}

// ---------------------------------------------------------------------------
// Kernel 3: GEMM2  agg = F @ H (+bias). *** R10: tile 320x256 -> grid
// 16 x 48 = 768 blocks = exactly 3.0 rounds on 256 CUs (1 block/CU by LDS),
// removing the 3.75->4 round quantization (6.25%). M-dimension-only retile
// of the R0-verified kernel: wave tile 160x64 (M-rep 10), acc 160 AGPR +
// ~96 VGPR (same 256 boundary R0 occupies at 128+128), LDS 2x(A 40K+B 32K)
// = 144KB. N-geometry, B staging, swizzle math, XCD locality profile are
// identical to R0 (12.9MB A working set per gg-phase; 1536 B-cols/XCD). ***
// 3-phase schedule (R0 invariants), counts scaled:
//  PH0: read afL(10) + b1(4); 40 MFMA afL x (b0,b1); bar
//  PH1: read afH(10); stage B(t+2) 4 DMA; 20 MFMA afH x b0; bar
//  PH2: stage A(t+2) 5 DMA; vmcnt(9); bar; b0(t+1) cross-read; 20 MFMA afH x b1
// Hazards: B last read PH0 -> staged PH1 after PH0's barrier; A last read
// PH1 -> staged PH2 after PH1's barrier. vmcnt(9)+bar: the 9 newest
// outstanding = t+2's own 9 loads -> t+1 fully landed before cross-read.
// ---------------------------------------------------------------------------
__global__ __launch_bounds__(512, 2) void gemm2(const unsigned short* __restrict__ A,
                                                const unsigned short* __restrict__ Bt,
                                                const float* __restrict__ bias,
                                                float* __restrict__ out) {
  __shared__ __align__(16) char sm[147456];   // 2 x (A 40KB + B 32KB)

  const int tid = threadIdx.x;
  const int l   = tid & 63;
  const int w   = tid >> 6;        // wave 0..7
  const int wr  = w >> 2;          // 0..1  (M): rows wr*160..+159
  const int wc  = w & 3;           // 0..3  (N)
  const int la  = l & 15;

  // XCD swizzle (bijective: 8 xcd x 4 gg x 4 m x 6 n = 768). Same locality
  // profile as R0: tM xcd-independent (A L3-shared), 6 N-tiles per XCD.
  const int xcd = blockIdx.x & 7;
  const int ii  = blockIdx.x >> 3;     // 0..95
  const int gg  = ii / 24;             // 0..3
  const int rmap= ii % 24;
  const long tM = (long)(gg * 4 + (rmap % 4)) * 320;
  const long tN = (long)(xcd * 6 + (rmap / 4)) * 256;

  // --- staging source (pre-swizzled global address; LDS dest linear; R0) ---
  const int  sRow  = l >> 3;
  const int  sCol8 = ((l & 7) ^ (l >> 3)) * 8;
  const unsigned short* gA2 = A  + (tM + sRow) * (size_t)KPAD + sCol8;
  const unsigned short* gB2 = Bt + (tN + sRow) * (size_t)KPAD + sCol8;

  // B: 2 loads covering 128 rows of one half (regionOff 40960 / 57344)
  auto stage2 = [&](int bufB, const unsigned short* g, int regionOff) {
    async16(g + (size_t)(w * 8)      * KPAD, (unsigned short*)(sm + bufB + regionOff + w * 1024));
    async16(g + (size_t)(w * 8 + 64) * KPAD, (unsigned short*)(sm + bufB + regionOff + (w + 8) * 1024));
  };
  // A: 5 loads covering 320 rows into region [0, 40960)
  auto stageA = [&](int bufB, const unsigned short* g) {
#pragma unroll
    for (int q = 0; q < 5; ++q)
      async16(g + (size_t)(w * 8 + q * 64) * KPAD,
              (unsigned short*)(sm + bufB + (w + q * 8) * 1024));
  };

  // --- hoisted swizzled ds_read base pointers (reads = base + m*2048) ---
  const int cOff0 = ((l >> 4) * 16)      ^ ((l & 7) << 4);
  const int cOff1 = (64 + (l >> 4) * 16) ^ ((l & 7) << 4);
  const int aRow  = (wr * 160 + la) * 128;
  const int bRow  = 40960 + (wc * 64 + la) * 128;
  const char* pA0[2] = { sm + aRow + cOff0, sm + 73728 + aRow + cOff0 };
  const char* pA1[2] = { sm + aRow + cOff1, sm + 73728 + aRow + cOff1 };
  const char* pB0[2] = { sm + bRow + cOff0, sm + 73728 + bRow + cOff0 };
  const char* pB1[2] = { sm + bRow + cOff1, sm + 73728 + bRow + cOff1 };

  f32x4  acc[10][4] = {};
  bf16x8 af[5][2], b0[2][2], b1[2][2];

  // mode: 0 steady; 1 = t=77 (no stage, vmcnt(0)); 2 = t=78 (tail).
  auto tile = [&](int bi, int mode) {
    const int bo = bi * 73728;
    const int ni = bi ^ 1;
    // ==== PH0: read afL(10) + b1(4); 40 MFMA afL x (b0,b1) ====
#pragma unroll
    for (int i2 = 0; i2 < 5; ++i2) {
      af[i2][0] = *(const bf16x8*)(pA0[bi] + i2 * 2048);
      af[i2][1] = *(const bf16x8*)(pA1[bi] + i2 * 2048);
    }
#pragma unroll
    for (int j = 0; j < 2; ++j) {
      b1[j][0] = *(const bf16x8*)(pB0[bi] + (2 + j) * 2048);
      b1[j][1] = *(const bf16x8*)(pB1[bi] + (2 + j) * 2048);
    }
    __builtin_amdgcn_s_setprio(1);
#pragma unroll
    for (int ks = 0; ks < 2; ++ks)
#pragma unroll
      for (int i2 = 0; i2 < 5; ++i2) {
#pragma unroll
        for (int j2 = 0; j2 < 2; ++j2)
          acc[i2][j2] = __builtin_amdgcn_mfma_f32_16x16x32_bf16(
              af[i2][ks], b0[j2][ks], acc[i2][j2], 0, 0, 0);
#pragma unroll
        for (int j2 = 0; j2 < 2; ++j2)
          acc[i2][2 + j2] = __builtin_amdgcn_mfma_f32_16x16x32_bf16(
              af[i2][ks], b1[j2][ks], acc[i2][2 + j2], 0, 0, 0);
      }
    __builtin_amdgcn_s_setprio(0);
    __builtin_amdgcn_s_barrier();
    // ==== PH1: read afH(10); stage B(t+2) -> bo; 20 MFMA afH x b0 ====
#pragma unroll
    for (int i2 = 0; i2 < 5; ++i2) {
      af[i2][0] = *(const bf16x8*)(pA0[bi] + (5 + i2) * 2048);
      af[i2][1] = *(const bf16x8*)(pA1[bi] + (5 + i2) * 2048);
    }
    if (mode == 0) {
      stage2(bo, gB2, 40960);
      stage2(bo, gB2 + (size_t)128 * KPAD, 57344);
      gB2 += 64;
    }
    __builtin_amdgcn_s_setprio(1);
#pragma unroll
    for (int ks = 0; ks < 2; ++ks)
#pragma unroll
      for (int i2 = 0; i2 < 5; ++i2)
#pragma unroll
        for (int j2 = 0; j2 < 2; ++j2)
          acc[5 + i2][j2] = __builtin_amdgcn_mfma_f32_16x16x32_bf16(
              af[i2][ks], b0[j2][ks], acc[5 + i2][j2], 0, 0, 0);
    __builtin_amdgcn_s_setprio(0);
    __builtin_amdgcn_s_barrier();
    // ==== PH2: stage A(t+2) -> bo; vmcnt(9); bar; b0(t+1); 20 MFMA afH x b1 ====
    if (mode == 0) {
      stageA(bo, gA2);
      gA2 += 64;
      asm volatile("s_waitcnt vmcnt(9)" ::: "memory");   // t+1 fully landed
    } else if (mode == 1) {
      asm volatile("s_waitcnt vmcnt(0)" ::: "memory");
    }
    __builtin_amdgcn_s_barrier();                         // globalizes vmcnt
    __builtin_amdgcn_sched_barrier(0);                    // pin reads below
    if (mode != 2) {
#pragma unroll
      for (int j = 0; j < 2; ++j) {
        b0[j][0] = *(const bf16x8*)(pB0[ni] + j * 2048);  // b0(t+1)
        b0[j][1] = *(const bf16x8*)(pB1[ni] + j * 2048);
      }
    }
    __builtin_amdgcn_s_setprio(1);
#pragma unroll
    for (int ks = 0; ks < 2; ++ks)
#pragma unroll
      for (int i2 = 0; i2 < 5; ++i2)
#pragma unroll
        for (int j2 = 0; j2 < 2; ++j2)
          acc[5 + i2][2 + j2] = __builtin_amdgcn_mfma_f32_16x16x32_bf16(
              af[i2][ks], b1[j2][ks], acc[5 + i2][2 + j2], 0, 0, 0);
    __builtin_amdgcn_s_setprio(0);
    // no trailing barrier: next PH0's reads are covered by this vmcnt+bar
  };

  // ---- prologue: stage t0 -> buf0, t1 -> buf1; pre-read b0(0) ----
  stage2(0, gB2, 40960); stage2(0, gB2 + (size_t)128 * KPAD, 57344);
  stageA(0, gA2);
  gA2 += 64; gB2 += 64;
  stage2(73728, gB2, 40960); stage2(73728, gB2 + (size_t)128 * KPAD, 57344);
  stageA(73728, gA2);
  gA2 += 64; gB2 += 64;       // -> tile 2 (first in-loop stage target)
  asm volatile("s_waitcnt vmcnt(9)" ::: "memory");   // t0's 9 loads retired
  __builtin_amdgcn_s_barrier();
  __builtin_amdgcn_sched_barrier(0);
#pragma unroll
  for (int j = 0; j < 2; ++j) {
    b0[j][0] = *(const bf16x8*)(pB0[0] + j * 2048);
    b0[j][1] = *(const bf16x8*)(pB1[0] + j * 2048);
  }

  // ---- main loop: t = 0..78 (79 K-tiles) ----
  for (int it = 0; it < 38; ++it) {    // t = 0..75
    tile(0, 0);
    tile(1, 0);
  }
  tile(0, 0);   // t=76: stages tile 78 into buf0
  tile(1, 1);   // t=77: drain, read b0(78) from buf0
  tile(0, 2);   // t=78: last

  // ---- epilogue: C/D map col=lane&15, row=(lane>>4)*4+reg ----
  float bv[4];
#pragma unroll
  for (int n = 0; n < 4; ++n) bv[n] = bias[n * 16 + la];
  const int rb = (l >> 4) * 4;
#pragma unroll
  for (int m = 0; m < 10; ++m) {
    long gm0 = tM + wr * 160 + m * 16 + rb;
#pragma unroll
    for (int rr2 = 0; rr2 < 4; ++rr2) {
      long gm = gm0 + rr2;
      if (gm < N_VERT) {
#pragma unroll
        for (int n = 0; n < 4; ++n) {
          long gn = tN + wc * 64 + n * 16 + la;
          out[gm * NCOL + gn] = acc[m][n][rr2] + bv[n];
        }
      }
    }
  }
}

extern "C" void kernel_launch(void* const* d_in, const int* in_sizes, int n_in,
                              void* d_out, int out_size, void* d_ws, size_t ws_size,
                              hipStream_t stream) {
  const float* x    = (const float*)d_in[0];
  const float* F    = (const float*)d_in[1];
  const float* W    = (const float*)d_in[2];
  const float* bias = (const float*)d_in[3];
  float* out = (float*)d_out;

  const size_t fbB = (size_t)MPAD * KPAD * 2;
  const size_t htB = (size_t)NCOL * KPAD * 2;
  if (ws_size < fbB + htB) return;

  unsigned short* Fb = (unsigned short*)d_ws;
  unsigned short* Ht = (unsigned short*)((char*)d_ws + fbB);

  prep <<<dim3(G1_BLOCKS + CVT_BLOCKS), 256, 0, stream>>>(x, W, F, Ht, Fb);
  gemm2<<<dim3(768),                    512, 0, stream>>>(Fb, Ht, bias, out);
}

// Round 11
// 625.536 us; speedup vs baseline: 2.2149x; 2.0655x over previous
//
#include <hip/hip_runtime.h>

// Problem constants
#define N_VERT 5000
#define NCOL   12288      // B*T*C_OUT reinterpreted columns
#define KPAD   5056       // 79*64: K padded (zero-filled)
#define MPAD   5120       // 20*256: M padded

#define G1_BLOCKS  15168  // 79*192 gemm1 blocks
#define CVT_BLOCKS 25280  // MPAD*(KPAD/4)/256

typedef float          f32x4  __attribute__((ext_vector_type(4)));
typedef unsigned short u16x4  __attribute__((ext_vector_type(4)));
typedef __bf16         bf16x8 __attribute__((ext_vector_type(8)));

__device__ __forceinline__ unsigned short f2bf(float f) {
  unsigned int u = __builtin_bit_cast(unsigned int, f);
  u += 0x7fffu + ((u >> 16) & 1u);   // RNE
  return (unsigned short)(u >> 16);
}

__device__ __forceinline__ void async16(const unsigned short* g, unsigned short* l) {
  __builtin_amdgcn_global_load_lds(
      (const __attribute__((address_space(1))) unsigned int*)g,
      (__attribute__((address_space(3))) unsigned int*)l, 16, 0, 0);
}

// ---------------------------------------------------------------------------
// Kernel P (merged prep, R7 MFMA version — measured at streaming floor):
// blocks [0, G1_BLOCKS) run GEMM1 (x@W -> Ht = H^T [col][KPAD], bf16) via
// MFMA with x split hi/lo bf16 (precision ~= fp32 GEMM); blocks
// [G1_BLOCKS, +CVT_BLOCKS) convert F -> Fb bf16 [MPAD][KPAD].
// MFMA layouts = gemm2's end-to-end-verified mappings:
//   A/B frag: lane l -> outdim = l&15, kchunk = l>>4 (8 contig k)
//   C/D:      col = l&15, row = (l>>4)*4 + reg
// LDS rows padded to 72 shorts (144 B): frag reads 16 rows stride 36 dwords
// -> banks {4*row mod 32} = 8 groups x 2 lanes = free 2-way.
// ---------------------------------------------------------------------------
__global__ __launch_bounds__(256) void prep(const float* __restrict__ x,
                                            const float* __restrict__ W,
                                            const float* __restrict__ F,
                                            unsigned short* __restrict__ Ht,
                                            unsigned short* __restrict__ Fb) {
  __shared__ unsigned short xh[64][72];   // x hi bf16, [u][c]
  __shared__ unsigned short xl[64][72];   // x lo bf16
  __shared__ unsigned short Wt[64][72];   // W^T bf16, [j][c]
  const int tid = threadIdx.x;

  if (blockIdx.x >= G1_BLOCKS) {
    int idx = (blockIdx.x - G1_BLOCKS) * 256 + tid;
    int row = idx / (KPAD / 4);
    int c4  = (idx % (KPAD / 4)) * 4;
    u16x4 o;
    if (row < N_VERT && c4 < N_VERT) {
      f32x4 v = *(const f32x4*)(F + (long)row * N_VERT + c4);
      o.x = f2bf(v.x); o.y = f2bf(v.y); o.z = f2bf(v.z); o.w = f2bf(v.w);
    } else {
      o.x = 0; o.y = 0; o.z = 0; o.w = 0;
    }
    *(u16x4*)(Fb + (long)row * KPAD + c4) = o;
    return;
  }

  const int utile = blockIdx.x % 79;   // 0..78
  const int rr    = blockIdx.x / 79;   // 0..191

  // W[c][j] -> Wt[j][c] bf16 (coalesced global read; scalar LDS store)
  for (int i = tid; i < 4096; i += 256) Wt[i & 63][i >> 6] = f2bf(W[i]);

  // x rows (u fixed, 64 c contiguous) -> xh/xl straight [u][c]
  {
    int rowu = tid >> 2;
    int cb   = (tid & 3) * 16;
    long u   = (long)utile * 64 + rowu;
    bool valid = (u < N_VERT);
    const float* src = x + (u * 192 + rr) * 64;
#pragma unroll
    for (int q = 0; q < 4; ++q) {
      int col = cb + q * 4;
      f32x4 v = {0.f, 0.f, 0.f, 0.f};
      if (valid) v = *(const f32x4*)(src + col);
      u16x4 h, lo;
#pragma unroll
      for (int e = 0; e < 4; ++e) {
        unsigned short hb = f2bf(v[e]);
        float hf = __builtin_bit_cast(float, (unsigned int)hb << 16);
        h[e]  = hb;
        lo[e] = f2bf(v[e] - hf);
      }
      *(u16x4*)&xh[rowu][col] = h;
      *(u16x4*)&xl[rowu][col] = lo;
    }
  }
  __syncthreads();

  // 4 waves; wave w owns j-block w*16. D[u][j] = x[u][c] @ W[c][j].
  const int l  = tid & 63;
  const int w  = tid >> 6;
  const int la = l & 15;
  const int ch = l >> 4;
  const int jb = w * 16;

  const char* xhp = (const char*)xh;
  const char* xlp = (const char*)xl;
  const char* wtp = (const char*)Wt;

  f32x4 acc[4] = {};
#pragma unroll
  for (int ks = 0; ks < 2; ++ks) {
    const int ko = ks * 64 + ch * 16;
    bf16x8 bfr = *(const bf16x8*)(wtp + (jb + la) * 144 + ko);
#pragma unroll
    for (int a = 0; a < 4; ++a) {
      bf16x8 al = *(const bf16x8*)(xlp + (a * 16 + la) * 144 + ko);
      bf16x8 ah = *(const bf16x8*)(xhp + (a * 16 + la) * 144 + ko);
      acc[a] = __builtin_amdgcn_mfma_f32_16x16x32_bf16(al, bfr, acc[a], 0, 0, 0);
      acc[a] = __builtin_amdgcn_mfma_f32_16x16x32_bf16(ah, bfr, acc[a], 0, 0, 0);
    }
  }

  // Store: lane l covers col = rr*64 + jb + la, k = utile*64 + a*16 + ch*4 + reg
  const long col = (long)rr * 64 + jb + la;
  const long kb  = (long)utile * 64 + ch * 4;
#pragma unroll
  for (int a = 0; a < 4; ++a) {
    u16x4 o = {f2bf(acc[a][0]), f2bf(acc[a][1]), f2bf(acc[a][2]), f2bf(acc[a][3])};
    *(u16x4*)(Ht + col * KPAD + kb + a * 16) = o;
  }
}

// ---------------------------------------------------------------------------
// Kernel 3: GEMM2  agg = F @ H (+bias). 256x256 tile, BK=64, 8 waves,
// 16x16x32 MFMA (verified fragment/swizzle layout), 3 phases / 3 barriers
// per K-tile (the empirical optimum across 6 structural variants):
//  PH0: read afL(8),b1(4); 32 MFMA afL x (b0,b1); bar
//  PH1: read afH(8); stage B(t+2); 16 MFMA afH x b0; bar
//  PH2: stage A(t+2); vmcnt(8); bar; b0(t+1) cross-read; 16 MFMA afH x b1
// Hazards: every phase's ds_reads complete before its own MFMA consumes them
// (in-order lgkmcnt), so the trailing barrier globalizes them before any DMA
// staging targets the region (B's last read: b1@PH0 -> stage@PH1; A's last:
// afH@PH1 -> stage@PH2). vmcnt(8)+bar globalizes tile t+1 before cross-read.
// ---------------------------------------------------------------------------
__global__ __launch_bounds__(512, 2) void gemm2(const unsigned short* __restrict__ A,
                                                const unsigned short* __restrict__ Bt,
                                                const float* __restrict__ bias,
                                                float* __restrict__ out) {
  __shared__ __align__(16) unsigned short smem[65536];
  char* sm = (char*)smem;

  const int tid = threadIdx.x;
  const int l   = tid & 63;
  const int w   = tid >> 6;        // wave 0..7
  const int wr  = w >> 2;          // 0..1  (M)
  const int wc  = w & 3;           // 0..3  (N)
  const int la  = l & 15;

  // Locality-grouped XCD swizzle (bijective: 8 xcd x 4 g x 5 m x 6 n = 960)
  const int xcd = blockIdx.x & 7;
  const int ii  = blockIdx.x >> 3;
  const int gg  = ii / 30;
  const int rmap= ii % 30;
  const long tM = (long)(gg * 5 + (rmap % 5)) * 256;
  const long tN = (long)(xcd * 6 + (rmap / 5)) * 256;

  // --- staging source (pre-swizzled global address; LDS dest linear) ---
  const int  sRow  = l >> 3;
  const int  sCol8 = ((l & 7) ^ (l >> 3)) * 8;
  const unsigned short* gA2 = A  + (tM + sRow) * (size_t)KPAD + sCol8;
  const unsigned short* gB2 = Bt + (tN + sRow) * (size_t)KPAD + sCol8;

  // 2 loads covering 128 rows of one operand region (bufB = BYTE offset)
  auto stage2 = [&](int bufB, const unsigned short* g, int regionOff) {
    async16(g + (size_t)(w * 8)      * KPAD, (unsigned short*)(sm + bufB + regionOff + w * 1024));
    async16(g + (size_t)(w * 8 + 64) * KPAD, (unsigned short*)(sm + bufB + regionOff + (w + 8) * 1024));
  };

  // --- hoisted swizzled ds_read base pointers (reads = base + m*2048) ---
  const int cOff0 = ((l >> 4) * 16)      ^ ((l & 7) << 4);
  const int cOff1 = (64 + (l >> 4) * 16) ^ ((l & 7) << 4);
  const int aRow  = (wr * 128 + la) * 128;
  const int bRow  = 32768 + (wc * 64 + la) * 128;
  const char* pA0[2] = { sm + aRow + cOff0, sm + 65536 + aRow + cOff0 };
  const char* pA1[2] = { sm + aRow + cOff1, sm + 65536 + aRow + cOff1 };
  const char* pB0[2] = { sm + bRow + cOff0, sm + 65536 + bRow + cOff0 };
  const char* pB1[2] = { sm + bRow + cOff1, sm + 65536 + bRow + cOff1 };

  f32x4  acc[8][4] = {};
  bf16x8 af[4][2], b0[2][2], b1[2][2];

#define MFMA_Q(AI, BJ, BV)                                                        \
  _Pragma("unroll")                                                               \
  for (int ks = 0; ks < 2; ++ks)                                                  \
    _Pragma("unroll")                                                             \
    for (int i2 = 0; i2 < 4; ++i2)                                                \
      _Pragma("unroll")                                                           \
      for (int j2 = 0; j2 < 2; ++j2)                                              \
        acc[AI][BJ] = __builtin_amdgcn_mfma_f32_16x16x32_bf16(                    \
            af[i2][ks], BV[j2][ks], acc[AI][BJ], 0, 0, 0);

  // mode: 0 steady; 1 = t=77 (no stage, vmcnt(0)); 2 = t=78 (tail).
  auto tile = [&](int bi, int mode) {
    const int bo = bi << 16;
    const int ni = bi ^ 1;
    // ==== PH0: read afL + b1(t); MFMA afL x b0 and afL x b1 (32) ====
#pragma unroll
    for (int i2 = 0; i2 < 4; ++i2) {
      af[i2][0] = *(const bf16x8*)(pA0[bi] + i2 * 2048);
      af[i2][1] = *(const bf16x8*)(pA1[bi] + i2 * 2048);
    }
#pragma unroll
    for (int j = 0; j < 2; ++j) {
      b1[j][0] = *(const bf16x8*)(pB0[bi] + (2 + j) * 2048);
      b1[j][1] = *(const bf16x8*)(pB1[bi] + (2 + j) * 2048);
    }
    __builtin_amdgcn_s_setprio(1);
    MFMA_Q(i2, j2, b0)
    MFMA_Q(i2, 2 + j2, b1)
    __builtin_amdgcn_s_setprio(0);
    __builtin_amdgcn_s_barrier();
    // ==== PH1: read afH; stage B(t+2) -> bo; MFMA afH x b0 (16) ====
#pragma unroll
    for (int i2 = 0; i2 < 4; ++i2) {
      af[i2][0] = *(const bf16x8*)(pA0[bi] + (4 + i2) * 2048);
      af[i2][1] = *(const bf16x8*)(pA1[bi] + (4 + i2) * 2048);
    }
    if (mode == 0) {
      stage2(bo, gB2, 32768);
      stage2(bo, gB2 + (size_t)128 * KPAD, 49152);
      gB2 += 64;
    }
    __builtin_amdgcn_s_setprio(1);
    MFMA_Q(4 + i2, j2, b0)
    __builtin_amdgcn_s_setprio(0);
    __builtin_amdgcn_s_barrier();
    // ==== PH2: stage A(t+2) -> bo; vmcnt(8); bar; b0(t+1); MFMA afH x b1 ====
    if (mode == 0) {
      stage2(bo, gA2, 0);
      stage2(bo, gA2 + (size_t)128 * KPAD, 16384);
      gA2 += 64;
      asm volatile("s_waitcnt vmcnt(8)" ::: "memory");   // t+1 fully landed
    } else if (mode == 1) {
      asm volatile("s_waitcnt vmcnt(0)" ::: "memory");
    }
    __builtin_amdgcn_s_barrier();                         // globalizes vmcnt
    __builtin_amdgcn_sched_barrier(0);                    // pin reads below
    if (mode != 2) {
#pragma unroll
      for (int j = 0; j < 2; ++j) {
        b0[j][0] = *(const bf16x8*)(pB0[ni] + j * 2048);  // b0(t+1)
        b0[j][1] = *(const bf16x8*)(pB1[ni] + j * 2048);
      }
    }
    __builtin_amdgcn_s_setprio(1);
    MFMA_Q(4 + i2, 2 + j2, b1)
    __builtin_amdgcn_s_setprio(0);
    // no trailing barrier: next PH0's reads are covered by this vmcnt+bar
  };

  // ---- prologue: stage t0 -> buf0, t1 -> buf1; pre-read b0(0) ----
  stage2(0, gB2, 32768); stage2(0, gB2 + (size_t)128 * KPAD, 49152);
  stage2(0, gA2, 0);     stage2(0, gA2 + (size_t)128 * KPAD, 16384);
  gA2 += 64; gB2 += 64;
  stage2(65536, gB2, 32768); stage2(65536, gB2 + (size_t)128 * KPAD, 49152);
  stage2(65536, gA2, 0);     stage2(65536, gA2 + (size_t)128 * KPAD, 16384);
  gA2 += 64; gB2 += 64;       // -> tile 2 (first in-loop stage target)
  asm volatile("s_waitcnt vmcnt(8)" ::: "memory");   // t0's 8 loads retired
  __builtin_amdgcn_s_barrier();
  __builtin_amdgcn_sched_barrier(0);
#pragma unroll
  for (int j = 0; j < 2; ++j) {
    b0[j][0] = *(const bf16x8*)(pB0[0] + j * 2048);
    b0[j][1] = *(const bf16x8*)(pB1[0] + j * 2048);
  }

  // ---- main loop: t = 0..78 (79 K-tiles) ----
  for (int it = 0; it < 38; ++it) {    // t = 0..75
    tile(0, 0);
    tile(1, 0);
  }
  tile(0, 0);   // t=76: stages tile 78 into buf0
  tile(1, 1);   // t=77: drain, read b0(78) from buf0
  tile(0, 2);   // t=78: last

#undef MFMA_Q

  // ---- epilogue: C/D map col=lane&15, row=(lane>>4)*4+reg ----
  float bv[4];
#pragma unroll
  for (int n = 0; n < 4; ++n) bv[n] = bias[n * 16 + la];
  const int rb = (l >> 4) * 4;
#pragma unroll
  for (int m = 0; m < 8; ++m) {
    long gm0 = tM + wr * 128 + m * 16 + rb;
#pragma unroll
    for (int rr2 = 0; rr2 < 4; ++rr2) {
      long gm = gm0 + rr2;
      if (gm < N_VERT) {
#pragma unroll
        for (int n = 0; n < 4; ++n) {
          long gn = tN + wc * 64 + n * 16 + la;
          out[gm * NCOL + gn] = acc[m][n][rr2] + bv[n];
        }
      }
    }
  }
}

extern "C" void kernel_launch(void* const* d_in, const int* in_sizes, int n_in,
                              void* d_out, int out_size, void* d_ws, size_t ws_size,
                              hipStream_t stream) {
  const float* x    = (const float*)d_in[0];
  const float* F    = (const float*)d_in[1];
  const float* W    = (const float*)d_in[2];
  const float* bias = (const float*)d_in[3];
  float* out = (float*)d_out;

  const size_t fbB = (size_t)MPAD * KPAD * 2;
  const size_t htB = (size_t)NCOL * KPAD * 2;
  if (ws_size < fbB + htB) return;

  unsigned short* Fb = (unsigned short*)d_ws;
  unsigned short* Ht = (unsigned short*)((char*)d_ws + fbB);

  prep <<<dim3(G1_BLOCKS + CVT_BLOCKS), 256, 0, stream>>>(x, W, F, Ht, Fb);
  gemm2<<<dim3(960),                    512, 0, stream>>>(Fb, Ht, bias, out);
}